// Round 1
// baseline (267.809 us; speedup 1.0000x reference)
//
#include <hip/hip_runtime.h>

#define DD 1024
#define HSZ 64
#define TT 2048
#define BBATCH 8
#define MM (BBATCH*TT)

typedef unsigned short U16;
typedef U16 u16x4 __attribute__((ext_vector_type(4)));
typedef U16 u16x8 __attribute__((ext_vector_type(8)));
typedef float f32x4 __attribute__((ext_vector_type(4)));

__device__ inline U16 f2b(float f) {
    unsigned u = __builtin_bit_cast(unsigned, f);
    u += 0x7FFFu + ((u >> 16) & 1u);
    return (U16)(u >> 16);
}

__device__ inline f32x4 mfma16(u16x8 a, u16x8 b, f32x4 c) {
    return __builtin_amdgcn_mfma_f32_16x16x32_bf16(a, b, c, 0, 0, 0);
}

// ---------------- QKV projection: [16384,1024] x 3x[64,1024]^T -> bf16 q,k,v ----------------
__global__ __launch_bounds__(256) void qkv_kernel(
    const float* __restrict__ x,
    const float* __restrict__ wq, const float* __restrict__ wqb,
    const float* __restrict__ wk, const float* __restrict__ wkb,
    const float* __restrict__ wv, const float* __restrict__ wvb,
    U16* __restrict__ qb, U16* __restrict__ kb, U16* __restrict__ vb)
{
    __shared__ __attribute__((aligned(16))) U16 As[64][72];
    __shared__ __attribute__((aligned(16))) U16 Bs[192][72];

    const int tid = threadIdx.x;
    const int m0 = blockIdx.x * 64;
    const int lane = tid & 63, w = tid >> 6;
    const int wm = w >> 1, wn = w & 1;
    const int g = lane >> 4, c = lane & 15;

    f32x4 acc[2][6] = {};

    for (int kt = 0; kt < DD / 64; ++kt) {
        __syncthreads();
        // stage x tile (fp32 -> bf16)
        for (int i = tid; i < 64 * 16; i += 256) {
            int row = i >> 4, c4 = i & 15;
            float4 v = *(const float4*)(x + (size_t)(m0 + row) * DD + kt * 64 + c4 * 4);
            u16x4 hv = { f2b(v.x), f2b(v.y), f2b(v.z), f2b(v.w) };
            *(u16x4*)&As[row][c4 * 4] = hv;
        }
        // stage weights tile: rows 0-63 = wq, 64-127 = wk, 128-191 = wv
        for (int i = tid; i < 192 * 16; i += 256) {
            int row = i >> 4, c4 = i & 15;
            const float* wp = row < 64 ? wq + (size_t)row * DD
                           : (row < 128 ? wk + (size_t)(row - 64) * DD
                                        : wv + (size_t)(row - 128) * DD);
            float4 v = *(const float4*)(wp + kt * 64 + c4 * 4);
            u16x4 hv = { f2b(v.x), f2b(v.y), f2b(v.z), f2b(v.w) };
            *(u16x4*)&Bs[row][c4 * 4] = hv;
        }
        __syncthreads();
        #pragma unroll
        for (int ks = 0; ks < 2; ++ks) {
            u16x8 a0 = *(const u16x8*)&As[wm * 32 + c][ks * 32 + g * 8];
            u16x8 a1 = *(const u16x8*)&As[wm * 32 + 16 + c][ks * 32 + g * 8];
            #pragma unroll
            for (int nf = 0; nf < 6; ++nf) {
                u16x8 bf = *(const u16x8*)&Bs[wn * 96 + nf * 16 + c][ks * 32 + g * 8];
                acc[0][nf] = mfma16(a0, bf, acc[0][nf]);
                acc[1][nf] = mfma16(a1, bf, acc[1][nf]);
            }
        }
    }

    // epilogue: bias add; Q pre-scaled by 1/sqrt(64)=0.125 (exact in bf16)
    #pragma unroll
    for (int mf = 0; mf < 2; ++mf)
        #pragma unroll
        for (int nf = 0; nf < 6; ++nf)
            #pragma unroll
            for (int r = 0; r < 4; ++r) {
                int row = m0 + wm * 32 + mf * 16 + g * 4 + r;
                int col = wn * 96 + nf * 16 + c;
                int head = col >> 6, h = col & 63;
                float bias = head == 0 ? wqb[h] : (head == 1 ? wkb[h] : wvb[h]);
                float val = acc[mf][nf][r] + bias;
                if (head == 0) val *= 0.125f;
                U16* dst = head == 0 ? qb : (head == 1 ? kb : vb);
                dst[(size_t)row * HSZ + h] = f2b(val);
            }
}

// ---------------- causal flash attention, 64-row Q tiles, 64-wide KV tiles ----------------
__global__ __launch_bounds__(256) void attn_kernel(
    const U16* __restrict__ qb, const U16* __restrict__ kb, const U16* __restrict__ vb,
    float* __restrict__ out)
{
    __shared__ __attribute__((aligned(16))) U16 Ks[64][72];
    __shared__ __attribute__((aligned(16))) U16 Vt[64][72];
    __shared__ __attribute__((aligned(16))) U16 Ps[4][16][72];

    const int tid = threadIdx.x, lane = tid & 63, w = tid >> 6;
    const int g = lane >> 4, c = lane & 15;
    const int q0 = blockIdx.x * 64;
    const size_t base = (size_t)blockIdx.y * TT;

    // Q fragments, kept in registers (Q already scaled by 0.125)
    u16x8 aq[2];
    {
        const U16* qp = qb + (base + q0 + w * 16 + c) * HSZ;
        aq[0] = *(const u16x8*)(qp + g * 8);
        aq[1] = *(const u16x8*)(qp + 32 + g * 8);
    }

    float mrow[4], lrow[4];
    f32x4 acc[4] = {};
    #pragma unroll
    for (int r = 0; r < 4; ++r) { mrow[r] = -1e30f; lrow[r] = 0.f; }

    const int qrow_base = q0 + w * 16 + g * 4;
    const int nt = blockIdx.x + 1;

    for (int t = 0; t < nt; ++t) {
        __syncthreads();
        // stage K row-major, V transposed
        for (int i = tid; i < 64 * 8; i += 256) {
            int row = i >> 3, c8 = i & 7;
            *(u16x8*)&Ks[row][c8 * 8] = *(const u16x8*)(kb + (base + t * 64 + row) * HSZ + c8 * 8);
            u16x8 v8 = *(const u16x8*)(vb + (base + t * 64 + row) * HSZ + c8 * 8);
            #pragma unroll
            for (int j = 0; j < 8; ++j) Vt[c8 * 8 + j][row] = v8[j];
        }
        __syncthreads();

        // S = Q K^T  (scale folded into Q)
        f32x4 s[4] = {};
        #pragma unroll
        for (int ks = 0; ks < 2; ++ks)
            #pragma unroll
            for (int nf = 0; nf < 4; ++nf) {
                u16x8 bf = *(const u16x8*)&Ks[nf * 16 + c][ks * 32 + g * 8];
                s[nf] = mfma16(aq[ks], bf, s[nf]);
            }

        // causal mask (only needed on/near the diagonal tile)
        if (t * 64 + 63 > q0) {
            #pragma unroll
            for (int nf = 0; nf < 4; ++nf)
                #pragma unroll
                for (int r = 0; r < 4; ++r)
                    if (t * 64 + nf * 16 + c > qrow_base + r) s[nf][r] = -1e30f;
        }

        // online softmax; stats per row live in the same lanes as the C-fragments
        float pv[4][4];
        #pragma unroll
        for (int r = 0; r < 4; ++r) {
            float pm = fmaxf(fmaxf(s[0][r], s[1][r]), fmaxf(s[2][r], s[3][r]));
            pm = fmaxf(pm, __shfl_xor(pm, 1));
            pm = fmaxf(pm, __shfl_xor(pm, 2));
            pm = fmaxf(pm, __shfl_xor(pm, 4));
            pm = fmaxf(pm, __shfl_xor(pm, 8));
            float mn = fmaxf(mrow[r], pm);
            float sc = __expf(mrow[r] - mn);
            mrow[r] = mn;
            float rs = 0.f;
            #pragma unroll
            for (int nf = 0; nf < 4; ++nf) { pv[nf][r] = __expf(s[nf][r] - mn); rs += pv[nf][r]; }
            rs += __shfl_xor(rs, 1); rs += __shfl_xor(rs, 2);
            rs += __shfl_xor(rs, 4); rs += __shfl_xor(rs, 8);
            lrow[r] = lrow[r] * sc + rs;
            #pragma unroll
            for (int nf = 0; nf < 4; ++nf) acc[nf][r] *= sc;
        }

        // P -> LDS (re-layout C-frag -> A-frag), wave-private buffer
        #pragma unroll
        for (int nf = 0; nf < 4; ++nf)
            #pragma unroll
            for (int r = 0; r < 4; ++r)
                Ps[w][g * 4 + r][nf * 16 + c] = f2b(pv[nf][r]);

        // O += P V
        #pragma unroll
        for (int ks = 0; ks < 2; ++ks) {
            u16x8 pa = *(const u16x8*)&Ps[w][c][ks * 32 + g * 8];
            #pragma unroll
            for (int nf = 0; nf < 4; ++nf) {
                u16x8 vf = *(const u16x8*)&Vt[nf * 16 + c][ks * 32 + g * 8];
                acc[nf] = mfma16(pa, vf, acc[nf]);
            }
        }
    }

    #pragma unroll
    for (int nf = 0; nf < 4; ++nf)
        #pragma unroll
        for (int r = 0; r < 4; ++r)
            out[(base + qrow_base + r) * HSZ + nf * 16 + c] = acc[nf][r] / lrow[r];
}

extern "C" void kernel_launch(void* const* d_in, const int* in_sizes, int n_in,
                              void* d_out, int out_size, void* d_ws, size_t ws_size,
                              hipStream_t stream) {
    const float* x   = (const float*)d_in[0];
    const float* wq  = (const float*)d_in[1];
    const float* wqb = (const float*)d_in[2];
    const float* wk  = (const float*)d_in[3];
    const float* wkb = (const float*)d_in[4];
    const float* wv  = (const float*)d_in[5];
    const float* wvb = (const float*)d_in[6];
    float* out = (float*)d_out;

    U16* qb = (U16*)d_ws;
    U16* kb = qb + (size_t)MM * HSZ;
    U16* vb = kb + (size_t)MM * HSZ;

    qkv_kernel<<<256, 256, 0, stream>>>(x, wq, wqb, wk, wkb, wv, wvb, qb, kb, vb);
    attn_kernel<<<dim3(32, BBATCH), 256, 0, stream>>>(qb, kb, vb, out);
}

// Round 2
// 178.228 us; speedup vs baseline: 1.5026x; 1.5026x over previous
//
#include <hip/hip_runtime.h>

#define DD 1024
#define HSZ 64
#define TT 2048
#define NB 8
#define MM (NB*TT)

typedef unsigned short U16;
typedef U16 u16x4 __attribute__((ext_vector_type(4)));
typedef U16 u16x8 __attribute__((ext_vector_type(8)));
typedef float f32x4 __attribute__((ext_vector_type(4)));

__device__ inline U16 f2b(float f) {
    unsigned u = __builtin_bit_cast(unsigned, f);
    u += 0x7FFFu + ((u >> 16) & 1u);
    return (U16)(u >> 16);
}

__device__ inline f32x4 mfma16(u16x8 a, u16x8 b, f32x4 c) {
    return __builtin_amdgcn_mfma_f32_16x16x32_bf16(a, b, c, 0, 0, 0);
}

__device__ inline void gld16(const void* g, void* l) {
    __builtin_amdgcn_global_load_lds(
        (const __attribute__((address_space(1))) void*)g,
        (__attribute__((address_space(3))) void*)l, 16, 0, 0);
}

// ---- weight preconvert: fp32 [192][1024] -> bf16, chunked [8][192][128], XOR-swizzled ----
__global__ __launch_bounds__(256) void wconv_kernel(
    const float* __restrict__ wq, const float* __restrict__ wk,
    const float* __restrict__ wv, U16* __restrict__ wb)
{
    int t = blockIdx.x * 256 + threadIdx.x;          // [0, 49152)
    int n = t >> 8;                                   // 192 rows
    int k0 = (t & 255) * 4;
    const float* src = n < 64 ? wq + (size_t)n * DD
                     : (n < 128 ? wk + (size_t)(n - 64) * DD
                                : wv + (size_t)(n - 128) * DD);
    float4 v = *(const float4*)(src + k0);
    int chunk = k0 >> 7, kc = k0 & 127;
    int byte = (n * 256 + kc * 2) ^ ((n & 7) << 4);
    u16x4 h = { f2b(v.x), f2b(v.y), f2b(v.z), f2b(v.w) };
    *(u16x4*)((char*)wb + (size_t)chunk * 49152 + byte) = h;
}

// ---- QKV projection: x[16384,1024]fp32 x W^T -> q,k bf16 row-major; v bf16 transposed ----
__global__ __launch_bounds__(512) void qkv_kernel(
    const float* __restrict__ x, const U16* __restrict__ wb,
    const float* __restrict__ wqb, const float* __restrict__ wkb, const float* __restrict__ wvb,
    U16* __restrict__ qb, U16* __restrict__ kb, U16* __restrict__ vt)
{
    __shared__ __attribute__((aligned(16))) U16 Bs[2][24576];  // 2 x [192][128] bf16, swizzled
    __shared__ __attribute__((aligned(16))) U16 As[2][8192];   // 2 x [64][128] bf16, swizzled

    const int tid = threadIdx.x, lane = tid & 63, w = tid >> 6;
    const int wm = w >> 1, wn = w & 1, g = lane >> 4, c = lane & 15;
    const int m0 = blockIdx.x * 64;

    // A reg-stage descriptors: thread -> (row, 16-float segment)
    const int arow = tid >> 3, aseg = tid & 7;
    const float* axp = x + (size_t)(m0 + arow) * DD + aseg * 16;
    const int abyte0 = (arow * 256 + aseg * 32) ^ ((arow & 7) << 4);
    const int abyte1 = (arow * 256 + aseg * 32 + 16) ^ ((arow & 7) << 4);

    f32x4 acc[6] = {};
    float4 ar0, ar1, ar2, ar3;

    // prologue: stage chunk 0
    {
        const float* p = axp;
        ar0 = *(const float4*)(p); ar1 = *(const float4*)(p + 4);
        ar2 = *(const float4*)(p + 8); ar3 = *(const float4*)(p + 12);
        const char* src = (const char*)wb + tid * 16;
        char* dst = (char*)&Bs[0][0] + tid * 16;
        #pragma unroll
        for (int it = 0; it < 6; ++it) gld16(src + it * 8192, dst + it * 8192);
        u16x8 h0 = { f2b(ar0.x), f2b(ar0.y), f2b(ar0.z), f2b(ar0.w),
                     f2b(ar1.x), f2b(ar1.y), f2b(ar1.z), f2b(ar1.w) };
        u16x8 h1 = { f2b(ar2.x), f2b(ar2.y), f2b(ar2.z), f2b(ar2.w),
                     f2b(ar3.x), f2b(ar3.y), f2b(ar3.z), f2b(ar3.w) };
        *(u16x8*)((char*)&As[0][0] + abyte0) = h0;
        *(u16x8*)((char*)&As[0][0] + abyte1) = h1;
    }
    __syncthreads();

    for (int ch = 0; ch < 8; ++ch) {
        const int cur = ch & 1, nxt = cur ^ 1;
        if (ch < 7) {
            // issue-early: next A tile (fp32->regs) + next B tile (DMA to LDS)
            const float* p = axp + (ch + 1) * 128;
            ar0 = *(const float4*)(p); ar1 = *(const float4*)(p + 4);
            ar2 = *(const float4*)(p + 8); ar3 = *(const float4*)(p + 12);
            const char* src = (const char*)wb + (size_t)(ch + 1) * 49152 + tid * 16;
            char* dst = (char*)&Bs[nxt][0] + tid * 16;
            #pragma unroll
            for (int it = 0; it < 6; ++it) gld16(src + it * 8192, dst + it * 8192);
        }
        // compute current chunk
        #pragma unroll
        for (int ks = 0; ks < 4; ++ks) {
            const int rl = wm * 16 + c;
            u16x8 af = *(const u16x8*)((const char*)&As[cur][0] +
                        ((rl * 256 + ks * 64 + g * 16) ^ ((c & 7) << 4)));
            #pragma unroll
            for (int nf = 0; nf < 6; ++nf) {
                const int n = wn * 96 + nf * 16 + c;
                u16x8 bf = *(const u16x8*)((const char*)&Bs[cur][0] +
                            ((n * 256 + ks * 64 + g * 16) ^ ((n & 7) << 4)));
                acc[nf] = mfma16(af, bf, acc[nf]);
            }
        }
        if (ch < 7) {
            // write-late: convert + ds_write next A tile
            u16x8 h0 = { f2b(ar0.x), f2b(ar0.y), f2b(ar0.z), f2b(ar0.w),
                         f2b(ar1.x), f2b(ar1.y), f2b(ar1.z), f2b(ar1.w) };
            u16x8 h1 = { f2b(ar2.x), f2b(ar2.y), f2b(ar2.z), f2b(ar2.w),
                         f2b(ar3.x), f2b(ar3.y), f2b(ar3.z), f2b(ar3.w) };
            *(u16x8*)((char*)&As[nxt][0] + abyte0) = h0;
            *(u16x8*)((char*)&As[nxt][0] + abyte1) = h1;
        }
        __syncthreads();
    }

    // epilogue: bias, Q-scale (1/8 exact), stores; V stored transposed [b][d][T]
    #pragma unroll
    for (int nf = 0; nf < 6; ++nf) {
        const int col = wn * 96 + nf * 16 + c;
        const int head = col >> 6, h = col & 63;
        const float bv = head == 0 ? wqb[h] : (head == 1 ? wkb[h] : wvb[h]);
        #pragma unroll
        for (int r = 0; r < 4; ++r) {
            const int row = m0 + wm * 16 + g * 4 + r;
            const float val = acc[nf][r] + bv;
            if (head == 0)      qb[(size_t)row * HSZ + h] = f2b(val * 0.125f);
            else if (head == 1) kb[(size_t)row * HSZ + h] = f2b(val);
            else {
                const int b = row >> 11, tok = row & 2047;
                vt[(size_t)b * (HSZ * TT) + (size_t)h * TT + tok] = f2b(val);
            }
        }
    }
}

// ---- barrier-free causal flash attention: 1 wave = one 16-row Q tile ----
__global__ __launch_bounds__(256) void attn_kernel(
    const U16* __restrict__ qb, const U16* __restrict__ kb, const U16* __restrict__ vt,
    float* __restrict__ out)
{
    __shared__ __attribute__((aligned(16))) U16 Ps[4][1024];  // per-wave 16x64 bf16, swizzled

    const int tid = threadIdx.x, lane = tid & 63, w = tid >> 6;
    const int g = lane >> 4, c = lane & 15;
    const int jid = blockIdx.x * 4 + w;        // [0,1024)
    const int batch = jid & 7, j = jid >> 3;   // j in [0,128)
    const int q0 = j * 16;
    const size_t base = (size_t)batch * TT;
    char* psw = (char*)&Ps[w][0];

    u16x8 aq[2];
    {
        const U16* qp = qb + (base + q0 + c) * HSZ;
        aq[0] = *(const u16x8*)(qp + g * 8);
        aq[1] = *(const u16x8*)(qp + 32 + g * 8);
    }

    f32x4 acc[4] = {};
    float mrow[4] = {-1e30f, -1e30f, -1e30f, -1e30f};
    float lrow[4] = {};
    const int nt = (j >> 2) + 1;
    const U16* vbase = vt + (size_t)batch * HSZ * TT;

    for (int t = 0; t < nt; ++t) {
        const size_t kvb = base + (size_t)t * 64;
        f32x4 s[4] = {};
        #pragma unroll
        for (int ks = 0; ks < 2; ++ks)
            #pragma unroll
            for (int nf = 0; nf < 4; ++nf) {
                u16x8 kf = *(const u16x8*)(kb + (kvb + nf * 16 + c) * HSZ + ks * 32 + g * 8);
                s[nf] = mfma16(aq[ks], kf, s[nf]);
            }
        // prefetch V fragments (direct from transposed global V)
        u16x8 vf[2][4];
        #pragma unroll
        for (int ks = 0; ks < 2; ++ks)
            #pragma unroll
            for (int nf = 0; nf < 4; ++nf)
                vf[ks][nf] = *(const u16x8*)(vbase + (size_t)(nf * 16 + c) * TT + t * 64 + ks * 32 + g * 8);

        if (t == nt - 1) {
            #pragma unroll
            for (int nf = 0; nf < 4; ++nf)
                #pragma unroll
                for (int r = 0; r < 4; ++r)
                    if (t * 64 + nf * 16 + c > q0 + g * 4 + r) s[nf][r] = -1e30f;
        }

        float pv[4][4];
        #pragma unroll
        for (int r = 0; r < 4; ++r) {
            float pm = fmaxf(fmaxf(s[0][r], s[1][r]), fmaxf(s[2][r], s[3][r]));
            pm = fmaxf(pm, __shfl_xor(pm, 1));
            pm = fmaxf(pm, __shfl_xor(pm, 2));
            pm = fmaxf(pm, __shfl_xor(pm, 4));
            pm = fmaxf(pm, __shfl_xor(pm, 8));
            const float mn = fmaxf(mrow[r], pm);
            const float sc = __expf(mrow[r] - mn);
            mrow[r] = mn;
            float rs = 0.f;
            #pragma unroll
            for (int nf = 0; nf < 4; ++nf) { pv[nf][r] = __expf(s[nf][r] - mn); rs += pv[nf][r]; }
            rs += __shfl_xor(rs, 1); rs += __shfl_xor(rs, 2);
            rs += __shfl_xor(rs, 4); rs += __shfl_xor(rs, 8);
            lrow[r] = lrow[r] * sc + rs;
            acc[0][r] *= sc; acc[1][r] *= sc; acc[2][r] *= sc; acc[3][r] *= sc;
        }

        // P -> wave-private swizzled LDS (C-frag -> A-frag re-layout), no barrier
        #pragma unroll
        for (int nf = 0; nf < 4; ++nf)
            #pragma unroll
            for (int r = 0; r < 4; ++r) {
                const int row = g * 4 + r, col = nf * 16 + c;
                *(U16*)(psw + ((row * 128 + col * 2) ^ ((row & 7) << 4))) = f2b(pv[nf][r]);
            }
        u16x8 pa[2];
        #pragma unroll
        for (int ks = 0; ks < 2; ++ks)
            pa[ks] = *(const u16x8*)(psw + ((c * 128 + ks * 64 + g * 16) ^ ((c & 7) << 4)));

        #pragma unroll
        for (int ks = 0; ks < 2; ++ks)
            #pragma unroll
            for (int nf = 0; nf < 4; ++nf)
                acc[nf] = mfma16(pa[ks], vf[ks][nf], acc[nf]);
    }

    #pragma unroll
    for (int nf = 0; nf < 4; ++nf)
        #pragma unroll
        for (int r = 0; r < 4; ++r)
            out[(base + q0 + g * 4 + r) * HSZ + nf * 16 + c] = acc[nf][r] / lrow[r];
}

extern "C" void kernel_launch(void* const* d_in, const int* in_sizes, int n_in,
                              void* d_out, int out_size, void* d_ws, size_t ws_size,
                              hipStream_t stream) {
    const float* x   = (const float*)d_in[0];
    const float* wq  = (const float*)d_in[1];
    const float* wqb = (const float*)d_in[2];
    const float* wk  = (const float*)d_in[3];
    const float* wkb = (const float*)d_in[4];
    const float* wv  = (const float*)d_in[5];
    const float* wvb = (const float*)d_in[6];
    float* out = (float*)d_out;

    U16* wb = (U16*)d_ws;                    // 8*49152 B = 393216 B
    U16* qb = wb + 196608;
    U16* kb = qb + (size_t)MM * HSZ;
    U16* vt = kb + (size_t)MM * HSZ;

    wconv_kernel<<<192, 256, 0, stream>>>(wq, wk, wv, wb);
    qkv_kernel<<<256, 512, 0, stream>>>(x, wb, wqb, wkb, wvb, qb, kb, vt);
    attn_kernel<<<256, 256, 0, stream>>>(qb, kb, vt, out);
}